// Round 2
// baseline (538.567 us; speedup 1.0000x reference)
//
#include <hip/hip_runtime.h>

// RelativePositionEncoding: out[1,1024,1024,128] f32 (537 MB, write-bound).
// out[i,j,:] = W_si[d_si] + W_ti[d_ti] + bent*w_ent + W_sym[d_sym]
// R2: drop the 71KB LDS W-tile (W is L1/L2-hot), keep only bins in LDS.
// R3: nt store -> cached store: NEUTRAL (533.7 us). Store flavor irrelevant.
// R4 (this round): latency/occupancy theory. Harness fill proves 6.2 TB/s
// pure-write; kernel itself is <338 us (absent from rocprof top-5) but the
// dependent chain (LDS bins -> 3 indexed W loads -> add -> store) at only
// 16 waves/CU leaves latency unhidden. Split each row i across 2 blocks
// (grid 2048, 2KB LDS) + __launch_bounds__(256,8) -> 32 waves/CU.

#define SEQ_L 1024
#define HALF  512
#define NW4   32   // float4 per 128-dim row

typedef float vf4 __attribute__((ext_vector_type(4)));

__global__ __launch_bounds__(256, 8)
void rpe_kernel(const int* __restrict__ seq_index,
                const int* __restrict__ seq_color,
                const int* __restrict__ seq_sym,
                const int* __restrict__ seq_entity,
                const int* __restrict__ token_index,
                const float* __restrict__ W,
                float* __restrict__ out)
{
    __shared__ int bins[HALF];   // 2 KB

    const int t     = threadIdx.x;
    const int b     = blockIdx.x;
    const int i     = b >> 1;          // row
    const int jbase = (b & 1) * HALF;  // which half of the row

    // Per-row (i) values — wave-uniform -> scalar loads.
    const int si_i  = seq_index[i];
    const int col_i = seq_color[i];
    const int sym_i = seq_sym[i];
    const int ent_i = seq_entity[i];
    const int ti_i  = token_index[i];

    // Packed bins for this block's j-range (2 iterations/thread).
    for (int jl = t; jl < HALF; jl += 256) {
        const int j  = jbase + jl;
        const int cj = seq_color[j];
        const int sj = seq_index[j];
        const int ej = seq_entity[j];
        int dsi = 65, dti = 65, dsym = 5, bent = 0;
        if (cj == col_i) {
            int d = si_i - sj;
            d = min(max(d, -32), 32) + 32;
            dsi = d;
            if (sj == si_i) {
                int dt = ti_i - token_index[j];
                dt = min(max(dt, -32), 32) + 32;
                dti = dt;
            }
        }
        if (ej == ent_i) {
            bent = 1;
            int ds = sym_i - seq_sym[j];
            ds = min(max(ds, -2), 2) + 2;
            dsym = ds;
        }
        bins[jl] = dsi | (dti << 8) | (dsym << 16) | (bent << 24);
    }
    __syncthreads();

    const int g  = t & 31;   // which float4 of the 32 covering 128 dims
    const int j0 = t >> 5;   // 8 local j's per block-iteration

    const vf4* W4 = (const vf4*)W;

    // Entity row slice in registers for the whole loop (L2-hot load).
    const vf4 went = W4[132 * NW4 + g];

    vf4* out4 = (vf4*)out + (size_t)i * (SEQ_L * NW4) + (size_t)jbase * NW4;

    #pragma unroll 4
    for (int jl = j0; jl < HALF; jl += 8) {
        const int pack = bins[jl];
        const int dsi  =  pack        & 0xff;
        const int dti  = (pack >> 8)  & 0xff;
        const int dsym = (pack >> 16) & 0xff;
        const float be = (float)(pack >> 24);  // 0 or 1

        // Coalesced 512B-per-half-wave loads, L1/L2 resident (W = 71 KB).
        const vf4 a = W4[dsi * NW4 + g];
        const vf4 b2 = W4[(66 + dti) * NW4 + g];
        const vf4 c = W4[(133 + dsym) * NW4 + g];

        vf4 r = a + b2 + c + be * went;

        out4[jl * NW4 + g] = r;   // plain cached store
    }
}

extern "C" void kernel_launch(void* const* d_in, const int* in_sizes, int n_in,
                              void* d_out, int out_size, void* d_ws, size_t ws_size,
                              hipStream_t stream) {
    const int*   seq_index   = (const int*)d_in[0];
    const int*   seq_color   = (const int*)d_in[1];
    const int*   seq_sym     = (const int*)d_in[2];
    const int*   seq_entity  = (const int*)d_in[3];
    const int*   token_index = (const int*)d_in[4];
    const float* W           = (const float*)d_in[5];
    float*       out         = (float*)d_out;

    rpe_kernel<<<SEQ_L * 2, 256, 0, stream>>>(seq_index, seq_color, seq_sym,
                                              seq_entity, token_index, W, out);
}

// Round 3
// 530.024 us; speedup vs baseline: 1.0161x; 1.0161x over previous
//
#include <hip/hip_runtime.h>

// RelativePositionEncoding: out[1,1024,1024,128] f32 (537 MB, write-bound).
// out[i,j,:] = W_si[d_si] + W_ti[d_ti] + bent*w_ent + W_sym[d_sym]
// R3: nt store -> cached store: NEUTRAL (533.7). R4: 32 waves/CU: NEUTRAL
// (538.6). Budget re-derivation: kernel ~100-110 us (store floor 87 us at
// the fill-proven 6.2 TB/s); timed region is dominated by harness poison
// fills (340 us for 2.1 GB + ~85 us for output).
// R5 (this round): fast-path kernel. 56% of pairs are all-miss
// (color!=, entity!=) -> output is one register constant, zero loads.
// Fold bent*w_ent into a 6-row LDS csym table (bent=1 <=> dsym<5), so the
// slow path is 2 L1 loads + 1 LDS read. Cuts load traffic ~85%.
// Pre-committed: third neutral result => fill-dominated account confirmed
// => ROOFLINE next round.

#define SEQ_L 1024
#define NW4   32   // float4 per 128-dim row

typedef float vf4 __attribute__((ext_vector_type(4)));

__global__ __launch_bounds__(256, 4)
void rpe_kernel(const int* __restrict__ seq_index,
                const int* __restrict__ seq_color,
                const int* __restrict__ seq_sym,
                const int* __restrict__ seq_entity,
                const int* __restrict__ token_index,
                const float* __restrict__ W,
                float* __restrict__ out)
{
    __shared__ int bins[SEQ_L];        // 4 KB
    __shared__ vf4 csym_l[6 * NW4];    // 3 KB: W_sym[k] (+ w_ent for k<5)

    const int t = threadIdx.x;
    const int i = blockIdx.x;
    const int g = t & 31;              // which float4 of the 128-dim row

    const vf4* W4 = (const vf4*)W;

    // Per-row (i) values — wave-uniform -> scalar loads.
    const int si_i  = seq_index[i];
    const int col_i = seq_color[i];
    const int sym_i = seq_sym[i];
    const int ent_i = seq_entity[i];
    const int ti_i  = token_index[i];

    // Build csym table: rows 0..4 = W_sym[k] + w_ent (bent=1 iff dsym<5),
    // row 5 = W_sym[5] (entity mismatch, bent=0). Exact fold, not approx.
    if (t < 6 * NW4) {
        const int k = t >> 5;          // 0..5
        vf4 v = W4[(133 + k) * NW4 + g];
        if (k < 5) v += W4[132 * NW4 + g];
        csym_l[t] = v;
    }

    // Packed bins for every j (once per block).
    for (int j = t; j < SEQ_L; j += 256) {
        const int cj = seq_color[j];
        const int sj = seq_index[j];
        const int ej = seq_entity[j];
        int dsi = 65, dti = 65, dsym = 5;
        if (cj == col_i) {
            int d = si_i - sj;
            d = min(max(d, -32), 32) + 32;
            dsi = d;
            if (sj == si_i) {
                int dt = ti_i - token_index[j];
                dt = min(max(dt, -32), 32) + 32;
                dti = dt;
            }
        }
        if (ej == ent_i) {
            int ds = sym_i - seq_sym[j];
            ds = min(max(ds, -2), 2) + 2;
            dsym = ds;
        }
        bins[j] = dsi | (dti << 8) | (dsym << 16);
    }
    __syncthreads();

    const int j0 = t >> 5;             // 8 j's per block-iteration

    // All-miss constant (56% of pairs): W_si[65] + W_ti[65] + W_sym[5].
    const vf4 amiss   = W4[65 * NW4 + g];
    const vf4 bmiss   = W4[131 * NW4 + g];
    const vf4 allmiss = (amiss + bmiss) + csym_l[5 * NW4 + g];

    const int MISSPACK = 65 | (65 << 8) | (5 << 16);   // 0x00054141

    vf4* out4 = (vf4*)out + (size_t)i * (SEQ_L * NW4);

    #pragma unroll 4
    for (int jl = j0; jl < SEQ_L; jl += 8) {
        const int pack = bins[jl];     // uniform per half-wave (j uniform)
        vf4 r;
        if (pack == MISSPACK) {
            r = allmiss;               // zero loads, zero adds
        } else {
            const int dsi  =  pack        & 0xff;
            const int dti  = (pack >> 8)  & 0xff;
            const int dsym = (pack >> 16) & 0xff;
            // Rows 65/131 ARE the miss rows, so unconditional loads are
            // correct even when only one of dsi/dti hit. L1/L2-hot.
            const vf4 a = W4[dsi * NW4 + g];
            const vf4 b = W4[(66 + dti) * NW4 + g];
            const vf4 c = csym_l[dsym * NW4 + g];
            r = (a + b) + c;
        }
        out4[jl * NW4 + g] = r;        // coalesced 512B per half-wave
    }
}

extern "C" void kernel_launch(void* const* d_in, const int* in_sizes, int n_in,
                              void* d_out, int out_size, void* d_ws, size_t ws_size,
                              hipStream_t stream) {
    const int*   seq_index   = (const int*)d_in[0];
    const int*   seq_color   = (const int*)d_in[1];
    const int*   seq_sym     = (const int*)d_in[2];
    const int*   seq_entity  = (const int*)d_in[3];
    const int*   token_index = (const int*)d_in[4];
    const float* W           = (const float*)d_in[5];
    float*       out         = (float*)d_out;

    rpe_kernel<<<SEQ_L, 256, 0, stream>>>(seq_index, seq_color, seq_sym,
                                          seq_entity, token_index, W, out);
}